// Round 6
// baseline (205.781 us; speedup 1.0000x reference)
//
#include <hip/hip_runtime.h>

#define T_SEQ 1024
#define D_MODEL 1024
#define NH 16
#define DH 64
#define R_SPAN 256.0f

typedef unsigned short ushort_t;
typedef __attribute__((ext_vector_type(8))) short bf16x8;
typedef __attribute__((ext_vector_type(4))) float f32x4;

// RNE conversion
__device__ __forceinline__ ushort_t f2bf(float f){
  union { float f; unsigned u; } v; v.f = f;
  unsigned r = v.u + 0x7fffu + ((v.u >> 16) & 1u);
  return (ushort_t)(r >> 16);
}

// round-half-up: 2 VALU ops, same 2^-9 rel-err bound (ties only differ)
__device__ __forceinline__ ushort_t f2bf_fast(float f){
  union { float f; unsigned u; } v; v.f = f;
  return (ushort_t)((v.u + 0x8000u) >> 16);
}

__device__ __forceinline__ float fast_exp2(float x){
#if __has_builtin(__builtin_amdgcn_exp2f)
  return __builtin_amdgcn_exp2f(x);
#else
  return __expf(x * 0.69314718056f);
#endif
}

typedef __attribute__((address_space(1))) void GV;
typedef __attribute__((address_space(3))) void LV;
__device__ __forceinline__ void gld16(const void* g, void* l){
  __builtin_amdgcn_global_load_lds((GV*)g, (LV*)l, 16, 0, 0);
}

// ---------------- weight conversion (x no longer converted) ----------------
__global__ void conv_w(const float* s1, const float* s2, const float* s3, const float* s4,
                       ushort_t* __restrict__ w_bf){
  const float* ws[4] = {s1, s2, s3, s4};
  const float* src = ws[blockIdx.y];
  ushort_t* dst = w_bf + ((size_t)blockIdx.y << 20);
  const int i = (blockIdx.x * 256 + threadIdx.x) * 4;
  float4 v = *(const float4*)(src + i);
  ushort4 o; o.x = f2bf(v.x); o.y = f2bf(v.y); o.z = f2bf(v.z); o.w = f2bf(v.w);
  *(ushort4*)(dst + i) = o;
}

// ---------------- mean over T ----------------
__global__ void mean_kernel(const float* __restrict__ x, float* __restrict__ xmean){
  const int b = blockIdx.y, d0 = blockIdx.x * 64;
  const int dl = threadIdx.x & 63, tg = threadIdx.x >> 6;
  const float* p = x + (size_t)b * T_SEQ * D_MODEL + d0 + dl;
  float s = 0.f;
  for (int t = tg * 256; t < tg * 256 + 256; ++t) s += p[(size_t)t * D_MODEL];
  __shared__ float red[4][64];
  red[tg][dl] = s;
  __syncthreads();
  if (tg == 0){
    float tot = red[0][dl] + red[1][dl] + red[2][dl] + red[3][dl];
    xmean[b * D_MODEL + d0 + dl] = tot * (1.0f / T_SEQ);
  }
}

// ---------------- span net ----------------
__global__ void span_kernel(const float* __restrict__ xmean, const float* __restrict__ Wspan,
                            const float* __restrict__ bspan, float* __restrict__ z){
  const int h = blockIdx.x, b = blockIdx.y, l = threadIdx.x;
  const float* xm = xmean + b * D_MODEL;
  const float* wv = Wspan + h * D_MODEL;
  float s = 0.f;
  for (int i = l; i < D_MODEL; i += 64) s += xm[i] * wv[i];
  for (int off = 32; off; off >>= 1) s += __shfl_down(s, off, 64);
  if (l == 0){
    float logit = s + bspan[h];
    z[b * NH + h] = (float)T_SEQ / (1.0f + __expf(-logit));
  }
}

// ---------------- GEMM: C = A * B^T, double-buffered ----------
// AFP32=1: A is fp32, staged via reg-prefetch (1 slab ahead) + cvt + ds_write.
template<int FP32OUT, int AFP32>
__global__ __launch_bounds__(256) void gemm_bt(
    const void* __restrict__ Ap,
    const ushort_t* __restrict__ B,
    void* __restrict__ C,
    const float* __restrict__ bias,
    const int M, const int N, const int K)
{
  __shared__ ushort_t At[2][128 * 32];
  __shared__ ushort_t Bt[2][128 * 32];

  const int z = blockIdx.z;
  const ushort_t* Bz = B + (size_t)z * N * K;

  const int tid = threadIdx.x;
  const int w = tid >> 6, lane = tid & 63;
  const int q = lane >> 4, c = lane & 15;
  const int m0 = blockIdx.y * 128, n0 = blockIdx.x * 128;
  const int wm = (w >> 1) * 64, wn = (w & 1) * 64;

  const int lr = lane >> 2;
  const int lc = (lane & 3) * 8;

  f32x4 acc[4][4] = {};

  const float*    Ax = (const float*)Ap;
  const ushort_t* Ab = (const ushort_t*)Ap;

  const ushort_t* ga0 = Ab + (size_t)(m0 + w * 16 + lr) * K + lc;
  const ushort_t* gb0 = Bz + (size_t)(n0 + w * 16 + lr) * K + lc;

  // fp32-A staging coords: 32 rows x 8 cols-of-4 per round, 4 rounds
  const int ar = tid >> 3, ac = (tid & 7) * 4;

  const int S = K >> 5;
  float4 a4[4];

  // prologue: stage slab 0 -> buf 0
  if (AFP32){
#pragma unroll
    for (int rr = 0; rr < 4; ++rr){
      float4 v = *(const float4*)(Ax + (size_t)(m0 + rr * 32 + ar) * K + ac);
      ushort4 o; o.x = f2bf(v.x); o.y = f2bf(v.y); o.z = f2bf(v.z); o.w = f2bf(v.w);
      *(ushort4*)&At[0][(rr * 32 + ar) * 32 + ac] = o;
    }
    if (S > 1){
#pragma unroll
      for (int rr = 0; rr < 4; ++rr)
        a4[rr] = *(const float4*)(Ax + (size_t)(m0 + rr * 32 + ar) * K + 32 + ac);
    }
  } else {
    gld16(ga0,                   &At[0][(w * 16) * 32]);
    gld16(ga0 + (size_t)64 * K,  &At[0][(64 + w * 16) * 32]);
  }
  gld16(gb0,                   &Bt[0][(w * 16) * 32]);
  gld16(gb0 + (size_t)64 * K,  &Bt[0][(64 + w * 16) * 32]);

  for (int s = 0; s < S; ++s){
    __syncthreads();  // slab s ready in buf[s&1]
    if (s + 1 < S){
      const int k0 = (s + 1) << 5;
      const int nb = (s + 1) & 1;
      if (AFP32){
        // a4 holds slab s+1 (loaded >=1 full iteration ago)
#pragma unroll
        for (int rr = 0; rr < 4; ++rr){
          ushort4 o; o.x = f2bf(a4[rr].x); o.y = f2bf(a4[rr].y);
          o.z = f2bf(a4[rr].z); o.w = f2bf(a4[rr].w);
          *(ushort4*)&At[nb][(rr * 32 + ar) * 32 + ac] = o;
        }
        if (s + 2 < S){
          const int k2 = (s + 2) << 5;
#pragma unroll
          for (int rr = 0; rr < 4; ++rr)
            a4[rr] = *(const float4*)(Ax + (size_t)(m0 + rr * 32 + ar) * K + k2 + ac);
        }
      } else {
        gld16(ga0 + k0,                   &At[nb][(w * 16) * 32]);
        gld16(ga0 + (size_t)64 * K + k0,  &At[nb][(64 + w * 16) * 32]);
      }
      gld16(gb0 + k0,                   &Bt[nb][(w * 16) * 32]);
      gld16(gb0 + (size_t)64 * K + k0,  &Bt[nb][(64 + w * 16) * 32]);
    }
    const ushort_t* at = At[s & 1];
    const ushort_t* bt = Bt[s & 1];

    bf16x8 af[4], bfv[4];
#pragma unroll
    for (int i = 0; i < 4; ++i) af[i]  = *(const bf16x8*)&at[(wm + i * 16 + c) * 32 + q * 8];
#pragma unroll
    for (int j = 0; j < 4; ++j) bfv[j] = *(const bf16x8*)&bt[(wn + j * 16 + c) * 32 + q * 8];
#pragma unroll
    for (int i = 0; i < 4; ++i)
#pragma unroll
      for (int j = 0; j < 4; ++j)
        acc[i][j] = __builtin_amdgcn_mfma_f32_16x16x32_bf16(af[i], bfv[j], acc[i][j], 0, 0, 0);
  }

  if (FP32OUT){
#pragma unroll
    for (int i = 0; i < 4; ++i){
#pragma unroll
      for (int j = 0; j < 4; ++j){
        const int row = m0 + wm + i * 16 + q * 4;
        const int col = n0 + wn + j * 16 + c;
#pragma unroll
        for (int r = 0; r < 4; ++r)
          ((float*)C)[(size_t)(row + r) * N + col] = acc[i][j][r] + bias[col];
      }
    }
  } else if (z == 2){
    // V: write transposed vt[b][n][t] so attn can stage V^T directly
    ushort_t* Cv = (ushort_t*)C + (size_t)2 * M * N;
    const int bb = m0 >> 10;
#pragma unroll
    for (int i = 0; i < 4; ++i){
#pragma unroll
      for (int j = 0; j < 4; ++j){
        const int col = n0 + wn + j * 16 + c;
        const int t0 = (m0 & 1023) + wm + i * 16 + q * 4;
        ushort4 pk;
        pk.x = f2bf_fast(acc[i][j][0]); pk.y = f2bf_fast(acc[i][j][1]);
        pk.z = f2bf_fast(acc[i][j][2]); pk.w = f2bf_fast(acc[i][j][3]);
        *(ushort4*)&Cv[((size_t)bb << 20) + (size_t)col * 1024 + t0] = pk;
      }
    }
  } else {
#pragma unroll
    for (int i = 0; i < 4; ++i){
#pragma unroll
      for (int j = 0; j < 4; ++j){
        const int row = m0 + wm + i * 16 + q * 4;
        const int col = n0 + wn + j * 16 + c;
#pragma unroll
        for (int r = 0; r < 4; ++r)
          ((ushort_t*)C + (size_t)z * M * N)[(size_t)(row + r) * N + col] = f2bf_fast(acc[i][j][r]);
      }
    }
  }
}

// ---------------- flash attention with adaptive span (v6) ----------------
// Bc=128 staging (2 compute halves per barrier pair), Q A-frags hoisted.
#define LPQ 72
#define VP 136
__global__ __launch_bounds__(512) void attn_kernel(
    const ushort_t* __restrict__ Qg,
    const ushort_t* __restrict__ Kg,
    const ushort_t* __restrict__ Vtg,
    const float* __restrict__ zspan,
    ushort_t* __restrict__ Og)
{
  __shared__ ushort_t Qs[128 * LPQ];
  __shared__ ushort_t Ks[128 * LPQ];
  __shared__ ushort_t Vt[64 * VP];      // [d][j0..j0+127]
  __shared__ ushort_t Ps[8][16 * LPQ];  // per-wave P band (64 wide)

  // id = (g/8)*64 + qt*8 + (g%8), g = b*16+h  ->  id%8 == g%8 (XCD locality)
  const int id = blockIdx.x;
  const int qt = (id >> 3) & 7;
  const int g  = ((id >> 6) << 3) | (id & 7);
  const int b = g >> 4, h = g & 15;
  const int q0 = qt * 128;
  const int tid = threadIdx.x, w = tid >> 6, lane = tid & 63;
  const int q = lane >> 4, c = lane & 15;

  const size_t base = ((size_t)b * T_SEQ) * D_MODEL + (size_t)h * DH;
  const ushort_t* vtb = Vtg + ((size_t)b << 20) + ((size_t)h << 16);

  // load Q tile (128x64)
  {
    const int row = tid >> 2, seg = tid & 3;
    const uint4* gq = (const uint4*)(Qg + base + (size_t)(q0 + row) * D_MODEL);
    uint4* qs = (uint4*)&Qs[row * LPQ];
    qs[seg * 2]     = gq[seg * 2];
    qs[seg * 2 + 1] = gq[seg * 2 + 1];
  }
  __syncthreads();
  // hoisted Q A-fragments (whole kernel)
  const bf16x8 aq0 = *(const bf16x8*)&Qs[(w * 16 + c) * LPQ + q * 8];
  const bf16x8 aq1 = *(const bf16x8*)&Qs[(w * 16 + c) * LPQ + 32 + q * 8];

  const float zz = zspan[b * NH + h];
  const int jend = min(T_SEQ, (int)(q0 + 127 + R_SPAN + zz) + 1);

  float d1[4] = {0, 0, 0, 0};
  f32x4 o[4] = {};

  const int wi0 = q0 + w * 16, wi1 = wi0 + 15;
  int i_row[4];
  float ar4[4];
#pragma unroll
  for (int r = 0; r < 4; ++r){
    i_row[r] = wi0 + q * 4 + r;
    ar4[r] = (R_SPAN + zz + (float)i_row[r]) * (1.0f / R_SPAN);
  }
  const float kexp = 0.125f * 1.44269504f;

  // staging coords (128-wide tiles)
  const int krow = tid >> 2, kseg = (tid & 3) * 16;       // K: 128 rows x 4x32B
  const int vrow = tid >> 3, vseg = (tid & 7) * 16;       // Vt: 64 rows x 8x32B
  const ushort_t* kgp = Kg + base + kseg;
  const ushort_t* vgp = vtb + (size_t)vrow * 1024 + vseg;

  // prefetch first tile
  uint4 ka = *(const uint4*)(kgp + (size_t)(q0 + krow) * D_MODEL);
  uint4 kb = *(const uint4*)(kgp + (size_t)(q0 + krow) * D_MODEL + 8);
  uint4 va = *(const uint4*)(vgp + q0);
  uint4 vb = *(const uint4*)(vgp + q0 + 8);

  for (int j0 = q0; j0 < jend; j0 += 128){
    __syncthreads();
    *(uint4*)&Ks[krow * LPQ + kseg]     = ka;
    *(uint4*)&Ks[krow * LPQ + kseg + 8] = kb;
    *(uint4*)&Vt[vrow * VP + vseg]      = va;
    *(uint4*)&Vt[vrow * VP + vseg + 8]  = vb;
    if (j0 + 128 < jend){
      ka = *(const uint4*)(kgp + (size_t)(j0 + 128 + krow) * D_MODEL);
      kb = *(const uint4*)(kgp + (size_t)(j0 + 128 + krow) * D_MODEL + 8);
      va = *(const uint4*)(vgp + j0 + 128);
      vb = *(const uint4*)(vgp + j0 + 128 + 8);
    }
    __syncthreads();

#pragma unroll
    for (int hh = 0; hh < 2; ++hh){
      const int j0h = j0 + hh * 64;
      if (j0h >= jend) break;
      if (j0h + 63 < wi0) continue;                       // fully causal-masked
      if ((float)(j0h - wi1) > R_SPAN + zz) continue;     // fully outside span

      // S = Q K^T  (16x64 band per wave)
      f32x4 s[4] = {};
#pragma unroll
      for (int jf = 0; jf < 4; ++jf){
        bf16x8 bk0 = *(const bf16x8*)&Ks[(hh * 64 + jf * 16 + c) * LPQ + q * 8];
        s[jf] = __builtin_amdgcn_mfma_f32_16x16x32_bf16(aq0, bk0, s[jf], 0, 0, 0);
        bf16x8 bk1 = *(const bf16x8*)&Ks[(hh * 64 + jf * 16 + c) * LPQ + 32 + q * 8];
        s[jf] = __builtin_amdgcn_mfma_f32_16x16x32_bf16(aq1, bk1, s[jf], 0, 0, 0);
      }

      const bool need_mask = (j0h <= wi1);
      const bool full = ((float)(j0h + 63 - wi0) <= zz);

      if (full){
        if (need_mask){
#pragma unroll
          for (int jf = 0; jf < 4; ++jf){
            const int j = j0h + jf * 16 + c;
#pragma unroll
            for (int r = 0; r < 4; ++r){
              float p = fast_exp2(s[jf][r] * kexp);
              p = (j >= i_row[r]) ? p : 0.f;
              d1[r] += p;
              Ps[w][(q * 4 + r) * LPQ + jf * 16 + c] = f2bf_fast(p);
            }
          }
        } else {
#pragma unroll
          for (int jf = 0; jf < 4; ++jf){
#pragma unroll
            for (int r = 0; r < 4; ++r){
              float p = fast_exp2(s[jf][r] * kexp);
              d1[r] += p;
              Ps[w][(q * 4 + r) * LPQ + jf * 16 + c] = f2bf_fast(p);
            }
          }
        }
      } else {
        float fjR[4];
#pragma unroll
        for (int jf = 0; jf < 4; ++jf) fjR[jf] = (float)(j0h + jf * 16 + c) * (1.0f / R_SPAN);
        if (need_mask){
#pragma unroll
          for (int jf = 0; jf < 4; ++jf){
            const int j = j0h + jf * 16 + c;
#pragma unroll
            for (int r = 0; r < 4; ++r){
              float p = fast_exp2(s[jf][r] * kexp);
              p = (j >= i_row[r]) ? p : 0.f;
              float chi = fminf(fmaxf(ar4[r] - fjR[jf], 0.f), 1.f);
              float pc = p * chi;
              d1[r] += pc;
              Ps[w][(q * 4 + r) * LPQ + jf * 16 + c] = f2bf_fast(pc);
            }
          }
        } else {
#pragma unroll
          for (int jf = 0; jf < 4; ++jf){
#pragma unroll
            for (int r = 0; r < 4; ++r){
              float p = fast_exp2(s[jf][r] * kexp);
              float chi = fminf(fmaxf(ar4[r] - fjR[jf], 0.f), 1.f);
              float pc = p * chi;
              d1[r] += pc;
              Ps[w][(q * 4 + r) * LPQ + jf * 16 + c] = f2bf_fast(pc);
            }
          }
        }
      }

      // O += P V  (Ps per-wave: no block barrier needed)
      {
        bf16x8 pa0 = *(const bf16x8*)&Ps[w][c * LPQ + q * 8];
        bf16x8 pa1 = *(const bf16x8*)&Ps[w][c * LPQ + 32 + q * 8];
#pragma unroll
        for (int nf = 0; nf < 4; ++nf){
          bf16x8 bv0 = *(const bf16x8*)&Vt[(nf * 16 + c) * VP + hh * 64 + q * 8];
          o[nf] = __builtin_amdgcn_mfma_f32_16x16x32_bf16(pa0, bv0, o[nf], 0, 0, 0);
          bf16x8 bv1 = *(const bf16x8*)&Vt[(nf * 16 + c) * VP + hh * 64 + 32 + q * 8];
          o[nf] = __builtin_amdgcn_mfma_f32_16x16x32_bf16(pa1, bv1, o[nf], 0, 0, 0);
        }
      }
    }
  }

  // epilogue: reduce d1 across 16 c-lanes, renormalize, write bf16
#pragma unroll
  for (int r = 0; r < 4; ++r){
    float a1 = d1[r];
    a1 += __shfl_xor(a1, 1, 64);
    a1 += __shfl_xor(a1, 2, 64);
    a1 += __shfl_xor(a1, 4, 64);
    a1 += __shfl_xor(a1, 8, 64);
    const float inv = 1.0f / (a1 + 1e-20f);
    const size_t rowbase = base + (size_t)i_row[r] * D_MODEL;
#pragma unroll
    for (int nf = 0; nf < 4; ++nf){
      Og[rowbase + nf * 16 + c] = f2bf_fast(o[nf][r] * inv);
    }
  }
}

// ---------------- launcher ----------------
extern "C" void kernel_launch(void* const* d_in, const int* in_sizes, int n_in,
                              void* d_out, int out_size, void* d_ws, size_t ws_size,
                              hipStream_t stream)
{
  const float* x     = (const float*)d_in[0];
  const float* Wq    = (const float*)d_in[1];
  const float* Wk    = (const float*)d_in[2];
  const float* Wv    = (const float*)d_in[3];
  const float* Wo    = (const float*)d_in[4];
  const float* bo    = (const float*)d_in[5];
  const float* Wspan = (const float*)d_in[6];
  const float* bspan = (const float*)d_in[7];

  const size_t MT = (size_t)4 * T_SEQ;  // 4096 rows

  ushort_t* w_bf = (ushort_t*)d_ws;                       // 4 * 1024*1024 bf16
  ushort_t* qkv  = w_bf + (size_t)4 * D_MODEL * D_MODEL;  // Q,K row-major; V transposed
  ushort_t* attn = qkv + (size_t)3 * MT * D_MODEL;        // 4096*1024 bf16
  float* xmean   = (float*)(attn + MT * D_MODEL);         // 4*1024 f32
  float* zsp     = xmean + 4 * D_MODEL;                   // 64 f32

  conv_w<<<dim3(1024, 4), 256, 0, stream>>>(Wq, Wk, Wv, Wo, w_bf);
  mean_kernel<<<dim3(16, 4), 256, 0, stream>>>(x, xmean);
  span_kernel<<<dim3(16, 4), 64, 0, stream>>>(xmean, Wspan, bspan, zsp);

  // fused Q,K,V projections from fp32 x (V written transposed)
  gemm_bt<0, 1><<<dim3(8, 32, 3), 256, 0, stream>>>(x, w_bf, qkv, nullptr, 4096, 1024, 1024);

  attn_kernel<<<dim3(512), 512, 0, stream>>>(qkv, qkv + MT * D_MODEL,
                                             qkv + 2 * MT * D_MODEL, zsp, attn);

  // output projection + bias, fp32 out
  gemm_bt<1, 0><<<dim3(8, 32, 1), 256, 0, stream>>>(attn, w_bf + (size_t)3 * D_MODEL * D_MODEL,
                                                    d_out, bo, 4096, 1024, 1024);
}

// Round 7
// 192.037 us; speedup vs baseline: 1.0716x; 1.0716x over previous
//
#include <hip/hip_runtime.h>

#define T_SEQ 1024
#define D_MODEL 1024
#define NH 16
#define DH 64
#define R_SPAN 256.0f

typedef unsigned short ushort_t;
typedef __attribute__((ext_vector_type(8))) short bf16x8;
typedef __attribute__((ext_vector_type(4))) float f32x4;

// RNE conversion (input conversion — feeds all GEMMs)
__device__ __forceinline__ ushort_t f2bf(float f){
  union { float f; unsigned u; } v; v.f = f;
  unsigned r = v.u + 0x7fffu + ((v.u >> 16) & 1u);
  return (ushort_t)(r >> 16);
}

// round-half-up: 2 VALU ops, same 2^-9 rel-err bound (ties only differ)
__device__ __forceinline__ ushort_t f2bf_fast(float f){
  union { float f; unsigned u; } v; v.f = f;
  return (ushort_t)((v.u + 0x8000u) >> 16);
}

__device__ __forceinline__ float fast_exp2(float x){
#if __has_builtin(__builtin_amdgcn_exp2f)
  return __builtin_amdgcn_exp2f(x);
#else
  return __expf(x * 0.69314718056f);
#endif
}

typedef __attribute__((address_space(1))) void GV;
typedef __attribute__((address_space(3))) void LV;
__device__ __forceinline__ void gld16(const void* g, void* l){
  __builtin_amdgcn_global_load_lds((GV*)g, (LV*)l, 16, 0, 0);
}

// ---------------- merged conversion kernel ----------------
// grid (1024, 8): chunks 0..3 = x (4 x 1M), 4..7 = Wq,Wk,Wv,Wo (1M each)
__global__ void conv_all(const float* __restrict__ x,
                         const float* s1, const float* s2, const float* s3, const float* s4,
                         ushort_t* __restrict__ x_bf, ushort_t* __restrict__ w_bf){
  const int chunk = blockIdx.y;
  const float* src;
  ushort_t* dst;
  if (chunk < 4){
    src = x + ((size_t)chunk << 20);
    dst = x_bf + ((size_t)chunk << 20);
  } else {
    const float* ws[4] = {s1, s2, s3, s4};
    src = ws[chunk - 4];
    dst = w_bf + ((size_t)(chunk - 4) << 20);
  }
  const int i = (blockIdx.x * 256 + threadIdx.x) * 4;
  float4 v = *(const float4*)(src + i);
  ushort4 o; o.x = f2bf(v.x); o.y = f2bf(v.y); o.z = f2bf(v.z); o.w = f2bf(v.w);
  *(ushort4*)(dst + i) = o;
}

// ---------------- mean over T ----------------
__global__ void mean_kernel(const float* __restrict__ x, float* __restrict__ xmean){
  const int b = blockIdx.y, d0 = blockIdx.x * 64;
  const int dl = threadIdx.x & 63, tg = threadIdx.x >> 6;
  const float* p = x + (size_t)b * T_SEQ * D_MODEL + d0 + dl;
  float s = 0.f;
  for (int t = tg * 256; t < tg * 256 + 256; ++t) s += p[(size_t)t * D_MODEL];
  __shared__ float red[4][64];
  red[tg][dl] = s;
  __syncthreads();
  if (tg == 0){
    float tot = red[0][dl] + red[1][dl] + red[2][dl] + red[3][dl];
    xmean[b * D_MODEL + d0 + dl] = tot * (1.0f / T_SEQ);
  }
}

// ---------------- span net ----------------
__global__ void span_kernel(const float* __restrict__ xmean, const float* __restrict__ Wspan,
                            const float* __restrict__ bspan, float* __restrict__ z){
  const int h = blockIdx.x, b = blockIdx.y, l = threadIdx.x;
  const float* xm = xmean + b * D_MODEL;
  const float* wv = Wspan + h * D_MODEL;
  float s = 0.f;
  for (int i = l; i < D_MODEL; i += 64) s += xm[i] * wv[i];
  for (int off = 32; off; off >>= 1) s += __shfl_down(s, off, 64);
  if (l == 0){
    float logit = s + bspan[h];
    z[b * NH + h] = (float)T_SEQ / (1.0f + __expf(-logit));
  }
}

// ---------------- GEMM: C = A * B^T, 128x128 tile, 8 waves (512 thr) ----------
// Each wave: 64x32 sub-tile (4x2 MFMA), 2 gld16 staging / slab, dbuf, 1 barrier.
// 8 waves/block x 3 blocks/CU = 24 waves/CU (vs 12 at 4-wave).
template<int FP32OUT>
__global__ __launch_bounds__(512) void gemm_bt(
    const ushort_t* __restrict__ A,
    const ushort_t* __restrict__ B,
    void* __restrict__ C,
    const float* __restrict__ bias,
    const int M, const int N, const int K)
{
  __shared__ ushort_t At[2][128 * 32];
  __shared__ ushort_t Bt[2][128 * 32];

  const int z = blockIdx.z;
  const ushort_t* Bz = B + (size_t)z * N * K;

  const int tid = threadIdx.x;
  const int w = tid >> 6, lane = tid & 63;
  const int q = lane >> 4, c = lane & 15;
  const int m0 = blockIdx.y * 128, n0 = blockIdx.x * 128;
  const int wm = (w >> 2) * 64, wn = (w & 3) * 32;

  const int lr = lane >> 2;
  const int lc = (lane & 3) * 8;

  f32x4 acc[4][2] = {};

  const ushort_t* ga0 = A  + (size_t)(m0 + w * 16 + lr) * K + lc;
  const ushort_t* gb0 = Bz + (size_t)(n0 + w * 16 + lr) * K + lc;

  const int S = K >> 5;
  gld16(ga0, &At[0][(w * 16) * 32]);
  gld16(gb0, &Bt[0][(w * 16) * 32]);

  for (int s = 0; s < S; ++s){
    __syncthreads();  // drains stage(s) [issued a full compute phase ago]
    if (s + 1 < S){
      const int k0 = (s + 1) << 5;
      const int nb = (s + 1) & 1;
      gld16(ga0 + k0, &At[nb][(w * 16) * 32]);
      gld16(gb0 + k0, &Bt[nb][(w * 16) * 32]);
    }
    const ushort_t* at = At[s & 1];
    const ushort_t* bt = Bt[s & 1];

    bf16x8 af[4], bfv[2];
#pragma unroll
    for (int i = 0; i < 4; ++i) af[i]  = *(const bf16x8*)&at[(wm + i * 16 + c) * 32 + q * 8];
#pragma unroll
    for (int j = 0; j < 2; ++j) bfv[j] = *(const bf16x8*)&bt[(wn + j * 16 + c) * 32 + q * 8];
#pragma unroll
    for (int i = 0; i < 4; ++i)
#pragma unroll
      for (int j = 0; j < 2; ++j)
        acc[i][j] = __builtin_amdgcn_mfma_f32_16x16x32_bf16(af[i], bfv[j], acc[i][j], 0, 0, 0);
  }

  if (FP32OUT){
#pragma unroll
    for (int i = 0; i < 4; ++i){
#pragma unroll
      for (int j = 0; j < 2; ++j){
        const int row = m0 + wm + i * 16 + q * 4;
        const int col = n0 + wn + j * 16 + c;
#pragma unroll
        for (int r = 0; r < 4; ++r)
          ((float*)C)[(size_t)(row + r) * N + col] = acc[i][j][r] + bias[col];
      }
    }
  } else if (z == 2){
    // V: write transposed vt[b][n][t] so attn can stage V^T directly
    ushort_t* Cv = (ushort_t*)C + (size_t)2 * M * N;
    const int bb = m0 >> 10;
#pragma unroll
    for (int i = 0; i < 4; ++i){
#pragma unroll
      for (int j = 0; j < 2; ++j){
        const int col = n0 + wn + j * 16 + c;
        const int t0 = (m0 & 1023) + wm + i * 16 + q * 4;
        ushort4 pk;
        pk.x = f2bf_fast(acc[i][j][0]); pk.y = f2bf_fast(acc[i][j][1]);
        pk.z = f2bf_fast(acc[i][j][2]); pk.w = f2bf_fast(acc[i][j][3]);
        *(ushort4*)&Cv[((size_t)bb << 20) + (size_t)col * 1024 + t0] = pk;
      }
    }
  } else {
#pragma unroll
    for (int i = 0; i < 4; ++i){
#pragma unroll
      for (int j = 0; j < 2; ++j){
        const int row = m0 + wm + i * 16 + q * 4;
        const int col = n0 + wn + j * 16 + c;
#pragma unroll
        for (int r = 0; r < 4; ++r)
          ((ushort_t*)C + (size_t)z * M * N)[(size_t)(row + r) * N + col] = f2bf_fast(acc[i][j][r]);
      }
    }
  }
}

// ---------------- flash attention with adaptive span (v7 = v5 + Q-frag hoist) --
#define LP 72
__global__ __launch_bounds__(512) void attn_kernel(
    const ushort_t* __restrict__ Qg,
    const ushort_t* __restrict__ Kg,
    const ushort_t* __restrict__ Vtg,
    const float* __restrict__ zspan,
    ushort_t* __restrict__ Og)
{
  __shared__ ushort_t Qs[128 * LP];
  __shared__ ushort_t Ks[64 * LP];
  __shared__ ushort_t Vt[64 * LP];     // [d][j]
  __shared__ ushort_t Ps[8][16 * LP];  // per-wave P band

  // id = (g/8)*64 + qt*8 + (g%8), g = b*16+h  ->  id%8 == g%8 (XCD locality)
  const int id = blockIdx.x;
  const int qt = (id >> 3) & 7;
  const int g  = ((id >> 6) << 3) | (id & 7);
  const int b = g >> 4, h = g & 15;
  const int q0 = qt * 128;
  const int tid = threadIdx.x, w = tid >> 6, lane = tid & 63;
  const int q = lane >> 4, c = lane & 15;

  const size_t base = ((size_t)b * T_SEQ) * D_MODEL + (size_t)h * DH;
  const ushort_t* vtb = Vtg + ((size_t)b << 20) + ((size_t)h << 16);

  // load Q tile (128x64): 512 threads x 32 B
  {
    const int row = tid >> 2, seg = tid & 3;
    const uint4* gq = (const uint4*)(Qg + base + (size_t)(q0 + row) * D_MODEL);
    uint4* qs = (uint4*)&Qs[row * LP];
    qs[seg * 2]     = gq[seg * 2];
    qs[seg * 2 + 1] = gq[seg * 2 + 1];
  }

  const float zz = zspan[b * NH + h];
  const int jend = min(T_SEQ, (int)(q0 + 127 + R_SPAN + zz) + 1);

  float d1[4] = {0, 0, 0, 0};
  f32x4 o[4] = {};

  const int wi0 = q0 + w * 16, wi1 = wi0 + 15;
  int i_row[4];
  float ar4[4];
#pragma unroll
  for (int r = 0; r < 4; ++r){
    i_row[r] = wi0 + q * 4 + r;
    ar4[r] = (R_SPAN + zz + (float)i_row[r]) * (1.0f / R_SPAN);
  }
  const float kexp = 0.125f * 1.44269504f;

  // staging coords: 64 rows x 8 segs of 8 elements
  const int srow = tid >> 3, sseg = tid & 7;
  const ushort_t* kg = Kg + base + sseg * 8;
  const ushort_t* vg = vtb + (size_t)srow * 1024 + sseg * 8;

  // prefetch first tile
  uint4 kreg = *(const uint4*)(kg + (size_t)(q0 + srow) * D_MODEL);
  uint4 vreg = *(const uint4*)(vg + q0);

  // hoisted Q A-fragments (constant over j-loop)
  __syncthreads();
  const bf16x8 aq0 = *(const bf16x8*)&Qs[(w * 16 + c) * LP + q * 8];
  const bf16x8 aq1 = *(const bf16x8*)&Qs[(w * 16 + c) * LP + 32 + q * 8];

  for (int j0 = q0; j0 < jend; j0 += 64){
    __syncthreads();
    *(uint4*)&Ks[srow * LP + sseg * 8] = kreg;
    *(uint4*)&Vt[srow * LP + sseg * 8] = vreg;
    if (j0 + 64 < jend){
      kreg = *(const uint4*)(kg + (size_t)(j0 + 64 + srow) * D_MODEL);
      vreg = *(const uint4*)(vg + j0 + 64);
    }
    __syncthreads();

    // per-wave skip: fully causal-masked or fully outside span
    if (j0 + 63 < wi0) continue;
    if ((float)(j0 - wi1) > R_SPAN + zz) continue;

    // S = Q K^T  (16x64 band per wave)
    f32x4 s[4] = {};
#pragma unroll
    for (int jf = 0; jf < 4; ++jf){
      bf16x8 bk0 = *(const bf16x8*)&Ks[(jf * 16 + c) * LP + q * 8];
      s[jf] = __builtin_amdgcn_mfma_f32_16x16x32_bf16(aq0, bk0, s[jf], 0, 0, 0);
      bf16x8 bk1 = *(const bf16x8*)&Ks[(jf * 16 + c) * LP + 32 + q * 8];
      s[jf] = __builtin_amdgcn_mfma_f32_16x16x32_bf16(aq1, bk1, s[jf], 0, 0, 0);
    }

    const bool need_mask = (j0 <= wi1);
    const bool full = ((float)(j0 + 63 - wi0) <= zz);

    if (full){
      if (need_mask){
#pragma unroll
        for (int jf = 0; jf < 4; ++jf){
          const int j = j0 + jf * 16 + c;
#pragma unroll
          for (int r = 0; r < 4; ++r){
            float p = fast_exp2(s[jf][r] * kexp);
            p = (j >= i_row[r]) ? p : 0.f;
            d1[r] += p;
            Ps[w][(q * 4 + r) * LP + jf * 16 + c] = f2bf_fast(p);
          }
        }
      } else {
#pragma unroll
        for (int jf = 0; jf < 4; ++jf){
#pragma unroll
          for (int r = 0; r < 4; ++r){
            float p = fast_exp2(s[jf][r] * kexp);
            d1[r] += p;
            Ps[w][(q * 4 + r) * LP + jf * 16 + c] = f2bf_fast(p);
          }
        }
      }
    } else {
      float fjR[4];
#pragma unroll
      for (int jf = 0; jf < 4; ++jf) fjR[jf] = (float)(j0 + jf * 16 + c) * (1.0f / R_SPAN);
      if (need_mask){
#pragma unroll
        for (int jf = 0; jf < 4; ++jf){
          const int j = j0 + jf * 16 + c;
#pragma unroll
          for (int r = 0; r < 4; ++r){
            float p = fast_exp2(s[jf][r] * kexp);
            p = (j >= i_row[r]) ? p : 0.f;
            float chi = fminf(fmaxf(ar4[r] - fjR[jf], 0.f), 1.f);
            float pc = p * chi;
            d1[r] += pc;
            Ps[w][(q * 4 + r) * LP + jf * 16 + c] = f2bf_fast(pc);
          }
        }
      } else {
#pragma unroll
        for (int jf = 0; jf < 4; ++jf){
#pragma unroll
          for (int r = 0; r < 4; ++r){
            float p = fast_exp2(s[jf][r] * kexp);
            float chi = fminf(fmaxf(ar4[r] - fjR[jf], 0.f), 1.f);
            float pc = p * chi;
            d1[r] += pc;
            Ps[w][(q * 4 + r) * LP + jf * 16 + c] = f2bf_fast(pc);
          }
        }
      }
    }

    // O += P V  (Ps per-wave: no block barrier needed)
    {
      bf16x8 pa0 = *(const bf16x8*)&Ps[w][c * LP + q * 8];
      bf16x8 pa1 = *(const bf16x8*)&Ps[w][c * LP + 32 + q * 8];
#pragma unroll
      for (int nf = 0; nf < 4; ++nf){
        bf16x8 bv0 = *(const bf16x8*)&Vt[(nf * 16 + c) * LP + q * 8];
        o[nf] = __builtin_amdgcn_mfma_f32_16x16x32_bf16(pa0, bv0, o[nf], 0, 0, 0);
        bf16x8 bv1 = *(const bf16x8*)&Vt[(nf * 16 + c) * LP + 32 + q * 8];
        o[nf] = __builtin_amdgcn_mfma_f32_16x16x32_bf16(pa1, bv1, o[nf], 0, 0, 0);
      }
    }
  }

  // epilogue: reduce d1 across 16 c-lanes, renormalize, write bf16
#pragma unroll
  for (int r = 0; r < 4; ++r){
    float a1 = d1[r];
    a1 += __shfl_xor(a1, 1, 64);
    a1 += __shfl_xor(a1, 2, 64);
    a1 += __shfl_xor(a1, 4, 64);
    a1 += __shfl_xor(a1, 8, 64);
    const float inv = 1.0f / (a1 + 1e-20f);
    const size_t rowbase = base + (size_t)i_row[r] * D_MODEL;
#pragma unroll
    for (int nf = 0; nf < 4; ++nf){
      Og[rowbase + nf * 16 + c] = f2bf_fast(o[nf][r] * inv);
    }
  }
}

// ---------------- launcher ----------------
extern "C" void kernel_launch(void* const* d_in, const int* in_sizes, int n_in,
                              void* d_out, int out_size, void* d_ws, size_t ws_size,
                              hipStream_t stream)
{
  const float* x     = (const float*)d_in[0];
  const float* Wq    = (const float*)d_in[1];
  const float* Wk    = (const float*)d_in[2];
  const float* Wv    = (const float*)d_in[3];
  const float* Wo    = (const float*)d_in[4];
  const float* bo    = (const float*)d_in[5];
  const float* Wspan = (const float*)d_in[6];
  const float* bspan = (const float*)d_in[7];

  const size_t MT = (size_t)4 * T_SEQ;  // 4096 rows

  ushort_t* x_bf = (ushort_t*)d_ws;                       // 4096*1024 bf16
  ushort_t* w_bf = x_bf + MT * D_MODEL;                   // 4 * 1024*1024 bf16
  ushort_t* qkv  = w_bf + (size_t)4 * D_MODEL * D_MODEL;  // Q,K row-major; V transposed
  ushort_t* attn = qkv + (size_t)3 * MT * D_MODEL;        // 4096*1024 bf16
  float* xmean   = (float*)(attn + MT * D_MODEL);         // 4*1024 f32
  float* zsp     = xmean + 4 * D_MODEL;                   // 64 f32

  conv_all<<<dim3(1024, 8), 256, 0, stream>>>(x, Wq, Wk, Wv, Wo, x_bf, w_bf);
  mean_kernel<<<dim3(16, 4), 256, 0, stream>>>(x, xmean);
  span_kernel<<<dim3(16, 4), 64, 0, stream>>>(xmean, Wspan, bspan, zsp);

  // fused Q,K,V projections (V written transposed)
  gemm_bt<0><<<dim3(8, 32, 3), 512, 0, stream>>>(x_bf, w_bf, qkv, nullptr, 4096, 1024, 1024);

  attn_kernel<<<dim3(512), 512, 0, stream>>>(qkv, qkv + MT * D_MODEL,
                                             qkv + 2 * MT * D_MODEL, zsp, attn);

  // output projection + bias, fp32 out
  gemm_bt<1><<<dim3(8, 32, 1), 512, 0, stream>>>(attn, w_bf + (size_t)3 * D_MODEL * D_MODEL,
                                                 d_out, bo, 4096, 1024, 1024);
}

// Round 8
// 191.443 us; speedup vs baseline: 1.0749x; 1.0031x over previous
//
#include <hip/hip_runtime.h>

#define T_SEQ 1024
#define D_MODEL 1024
#define NH 16
#define DH 64
#define R_SPAN 256.0f

typedef unsigned short ushort_t;
typedef __attribute__((ext_vector_type(8))) short bf16x8;
typedef __attribute__((ext_vector_type(4))) float f32x4;

// RNE conversion (input conversion — feeds all GEMMs)
__device__ __forceinline__ ushort_t f2bf(float f){
  union { float f; unsigned u; } v; v.f = f;
  unsigned r = v.u + 0x7fffu + ((v.u >> 16) & 1u);
  return (ushort_t)(r >> 16);
}

// round-half-up: 2 VALU ops, same 2^-9 rel-err bound (ties only differ)
__device__ __forceinline__ ushort_t f2bf_fast(float f){
  union { float f; unsigned u; } v; v.f = f;
  return (ushort_t)((v.u + 0x8000u) >> 16);
}

__device__ __forceinline__ float fast_exp2(float x){
#if __has_builtin(__builtin_amdgcn_exp2f)
  return __builtin_amdgcn_exp2f(x);
#else
  return __expf(x * 0.69314718056f);
#endif
}

// barrier that drains LDS (lgkmcnt=0) but leaves global loads in flight
// (vmcnt=63): simm16 = vmcnt[3:0]=0xF | expcnt=7<<4 | lgkm=0<<8 | vmcnt[5:4]=3<<14
__device__ __forceinline__ void barrier_lds_only(){
  __builtin_amdgcn_s_waitcnt(0xC07F);
  __builtin_amdgcn_s_barrier();
}

typedef __attribute__((address_space(1))) void GV;
typedef __attribute__((address_space(3))) void LV;
__device__ __forceinline__ void gld16(const void* g, void* l){
  __builtin_amdgcn_global_load_lds((GV*)g, (LV*)l, 16, 0, 0);
}

// ---------------- merged conversion kernel ----------------
// grid (1024, 8): chunks 0..3 = x (4 x 1M), 4..7 = Wq,Wk,Wv,Wo (1M each)
__global__ void conv_all(const float* __restrict__ x,
                         const float* s1, const float* s2, const float* s3, const float* s4,
                         ushort_t* __restrict__ x_bf, ushort_t* __restrict__ w_bf){
  const int chunk = blockIdx.y;
  const float* src;
  ushort_t* dst;
  if (chunk < 4){
    src = x + ((size_t)chunk << 20);
    dst = x_bf + ((size_t)chunk << 20);
  } else {
    const float* ws[4] = {s1, s2, s3, s4};
    src = ws[chunk - 4];
    dst = w_bf + ((size_t)(chunk - 4) << 20);
  }
  const int i = (blockIdx.x * 256 + threadIdx.x) * 4;
  float4 v = *(const float4*)(src + i);
  ushort4 o; o.x = f2bf(v.x); o.y = f2bf(v.y); o.z = f2bf(v.z); o.w = f2bf(v.w);
  *(ushort4*)(dst + i) = o;
}

// ---------------- mean over T ----------------
__global__ void mean_kernel(const float* __restrict__ x, float* __restrict__ xmean){
  const int b = blockIdx.y, d0 = blockIdx.x * 64;
  const int dl = threadIdx.x & 63, tg = threadIdx.x >> 6;
  const float* p = x + (size_t)b * T_SEQ * D_MODEL + d0 + dl;
  float s = 0.f;
  for (int t = tg * 256; t < tg * 256 + 256; ++t) s += p[(size_t)t * D_MODEL];
  __shared__ float red[4][64];
  red[tg][dl] = s;
  __syncthreads();
  if (tg == 0){
    float tot = red[0][dl] + red[1][dl] + red[2][dl] + red[3][dl];
    xmean[b * D_MODEL + d0 + dl] = tot * (1.0f / T_SEQ);
  }
}

// ---------------- span net ----------------
__global__ void span_kernel(const float* __restrict__ xmean, const float* __restrict__ Wspan,
                            const float* __restrict__ bspan, float* __restrict__ z){
  const int h = blockIdx.x, b = blockIdx.y, l = threadIdx.x;
  const float* xm = xmean + b * D_MODEL;
  const float* wv = Wspan + h * D_MODEL;
  float s = 0.f;
  for (int i = l; i < D_MODEL; i += 64) s += xm[i] * wv[i];
  for (int off = 32; off; off >>= 1) s += __shfl_down(s, off, 64);
  if (l == 0){
    float logit = s + bspan[h];
    z[b * NH + h] = (float)T_SEQ / (1.0f + __expf(-logit));
  }
}

// ---------------- GEMM: C = A * B^T, 128x128 tile, 8 waves (512 thr) ----------
template<int FP32OUT>
__global__ __launch_bounds__(512) void gemm_bt(
    const ushort_t* __restrict__ A,
    const ushort_t* __restrict__ B,
    void* __restrict__ C,
    const float* __restrict__ bias,
    const int M, const int N, const int K)
{
  __shared__ ushort_t At[2][128 * 32];
  __shared__ ushort_t Bt[2][128 * 32];

  const int z = blockIdx.z;
  const ushort_t* Bz = B + (size_t)z * N * K;

  const int tid = threadIdx.x;
  const int w = tid >> 6, lane = tid & 63;
  const int q = lane >> 4, c = lane & 15;
  const int m0 = blockIdx.y * 128, n0 = blockIdx.x * 128;
  const int wm = (w >> 2) * 64, wn = (w & 3) * 32;

  const int lr = lane >> 2;
  const int lc = (lane & 3) * 8;

  f32x4 acc[4][2] = {};

  const ushort_t* ga0 = A  + (size_t)(m0 + w * 16 + lr) * K + lc;
  const ushort_t* gb0 = Bz + (size_t)(n0 + w * 16 + lr) * K + lc;

  const int S = K >> 5;
  gld16(ga0, &At[0][(w * 16) * 32]);
  gld16(gb0, &Bt[0][(w * 16) * 32]);

  for (int s = 0; s < S; ++s){
    __syncthreads();  // drains stage(s) [issued a full compute phase ago]
    if (s + 1 < S){
      const int k0 = (s + 1) << 5;
      const int nb = (s + 1) & 1;
      gld16(ga0 + k0, &At[nb][(w * 16) * 32]);
      gld16(gb0 + k0, &Bt[nb][(w * 16) * 32]);
    }
    const ushort_t* at = At[s & 1];
    const ushort_t* bt = Bt[s & 1];

    bf16x8 af[4], bfv[2];
#pragma unroll
    for (int i = 0; i < 4; ++i) af[i]  = *(const bf16x8*)&at[(wm + i * 16 + c) * 32 + q * 8];
#pragma unroll
    for (int j = 0; j < 2; ++j) bfv[j] = *(const bf16x8*)&bt[(wn + j * 16 + c) * 32 + q * 8];
#pragma unroll
    for (int i = 0; i < 4; ++i)
#pragma unroll
      for (int j = 0; j < 2; ++j)
        acc[i][j] = __builtin_amdgcn_mfma_f32_16x16x32_bf16(af[i], bfv[j], acc[i][j], 0, 0, 0);
  }

  if (FP32OUT){
#pragma unroll
    for (int i = 0; i < 4; ++i){
#pragma unroll
      for (int j = 0; j < 2; ++j){
        const int row = m0 + wm + i * 16 + q * 4;
        const int col = n0 + wn + j * 16 + c;
#pragma unroll
        for (int r = 0; r < 4; ++r)
          ((float*)C)[(size_t)(row + r) * N + col] = acc[i][j][r] + bias[col];
      }
    }
  } else if (z == 2){
    // V: write transposed vt[b][n][t] so attn can stage V^T directly
    ushort_t* Cv = (ushort_t*)C + (size_t)2 * M * N;
    const int bb = m0 >> 10;
#pragma unroll
    for (int i = 0; i < 4; ++i){
#pragma unroll
      for (int j = 0; j < 2; ++j){
        const int col = n0 + wn + j * 16 + c;
        const int t0 = (m0 & 1023) + wm + i * 16 + q * 4;
        ushort4 pk;
        pk.x = f2bf_fast(acc[i][j][0]); pk.y = f2bf_fast(acc[i][j][1]);
        pk.z = f2bf_fast(acc[i][j][2]); pk.w = f2bf_fast(acc[i][j][3]);
        *(ushort4*)&Cv[((size_t)bb << 20) + (size_t)col * 1024 + t0] = pk;
      }
    }
  } else {
#pragma unroll
    for (int i = 0; i < 4; ++i){
#pragma unroll
      for (int j = 0; j < 2; ++j){
        const int row = m0 + wm + i * 16 + q * 4;
        const int col = n0 + wn + j * 16 + c;
#pragma unroll
        for (int r = 0; r < 4; ++r)
          ((ushort_t*)C + (size_t)z * M * N)[(size_t)(row + r) * N + col] = f2bf_fast(acc[i][j][r]);
      }
    }
  }
}

// ---------------- flash attention with adaptive span (v8) ----------------
// K/V double-buffered: ONE barrier per j-tile, and the barrier waits
// lgkmcnt(0) only (vmcnt left in flight) so the register prefetch of tile
// j+1 is genuinely hidden behind tile j's compute (the __syncthreads
// vmcnt(0)-drain was exposing it every tile).
#define LP 72
__global__ __launch_bounds__(512) void attn_kernel(
    const ushort_t* __restrict__ Qg,
    const ushort_t* __restrict__ Kg,
    const ushort_t* __restrict__ Vtg,
    const float* __restrict__ zspan,
    ushort_t* __restrict__ Og)
{
  __shared__ ushort_t Qs[128 * LP];
  __shared__ ushort_t Ks[2][64 * LP];
  __shared__ ushort_t Vt[2][64 * LP];  // [d][j]
  __shared__ ushort_t Ps[8][16 * LP];  // per-wave P band

  // id = (g/8)*64 + qt*8 + (g%8), g = b*16+h  ->  id%8 == g%8 (XCD locality)
  const int id = blockIdx.x;
  const int qt = (id >> 3) & 7;
  const int g  = ((id >> 6) << 3) | (id & 7);
  const int b = g >> 4, h = g & 15;
  const int q0 = qt * 128;
  const int tid = threadIdx.x, w = tid >> 6, lane = tid & 63;
  const int q = lane >> 4, c = lane & 15;

  const size_t base = ((size_t)b * T_SEQ) * D_MODEL + (size_t)h * DH;
  const ushort_t* vtb = Vtg + ((size_t)b << 20) + ((size_t)h << 16);

  // load Q tile (128x64): 512 threads x 32 B
  {
    const int row = tid >> 2, seg = tid & 3;
    const uint4* gq = (const uint4*)(Qg + base + (size_t)(q0 + row) * D_MODEL);
    uint4* qs = (uint4*)&Qs[row * LP];
    qs[seg * 2]     = gq[seg * 2];
    qs[seg * 2 + 1] = gq[seg * 2 + 1];
  }

  const float zz = zspan[b * NH + h];
  const int jend = min(T_SEQ, (int)(q0 + 127 + R_SPAN + zz) + 1);

  float d1[4] = {0, 0, 0, 0};
  f32x4 o[4] = {};

  const int wi0 = q0 + w * 16, wi1 = wi0 + 15;
  int i_row[4];
  float ar4[4];
#pragma unroll
  for (int r = 0; r < 4; ++r){
    i_row[r] = wi0 + q * 4 + r;
    ar4[r] = (R_SPAN + zz + (float)i_row[r]) * (1.0f / R_SPAN);
  }
  const float kexp = 0.125f * 1.44269504f;

  // staging coords: 64 rows x 8 segs of 8 elements
  const int srow = tid >> 3, sseg = tid & 7;
  const ushort_t* kg = Kg + base + sseg * 8;
  const ushort_t* vg = vtb + (size_t)srow * 1024 + sseg * 8;

  // prefetch first tile
  uint4 kreg = *(const uint4*)(kg + (size_t)(q0 + srow) * D_MODEL);
  uint4 vreg = *(const uint4*)(vg + q0);

  // Qs visible to all waves; hoist Q A-fragments (constant over j-loop)
  __syncthreads();
  const bf16x8 aq0 = *(const bf16x8*)&Qs[(w * 16 + c) * LP + q * 8];
  const bf16x8 aq1 = *(const bf16x8*)&Qs[(w * 16 + c) * LP + 32 + q * 8];

  int it = 0;
  for (int j0 = q0; j0 < jend; j0 += 64, ++it){
    const int buf = it & 1;
    // write tile j0 (regs were loaded >=1 compute-phase ago; compiler waits
    // vmcnt here, not at the barrier)
    *(uint4*)&Ks[buf][srow * LP + sseg * 8] = kreg;
    *(uint4*)&Vt[buf][srow * LP + sseg * 8] = vreg;
    if (j0 + 64 < jend){
      kreg = *(const uint4*)(kg + (size_t)(j0 + 64 + srow) * D_MODEL);
      vreg = *(const uint4*)(vg + j0 + 64);
    }
    barrier_lds_only();  // LDS writes visible; prefetch stays in flight

    // per-wave skip: fully causal-masked or fully outside span
    if (j0 + 63 < wi0) continue;
    if ((float)(j0 - wi1) > R_SPAN + zz) continue;

    // S = Q K^T  (16x64 band per wave)
    f32x4 s[4] = {};
#pragma unroll
    for (int jf = 0; jf < 4; ++jf){
      bf16x8 bk0 = *(const bf16x8*)&Ks[buf][(jf * 16 + c) * LP + q * 8];
      s[jf] = __builtin_amdgcn_mfma_f32_16x16x32_bf16(aq0, bk0, s[jf], 0, 0, 0);
      bf16x8 bk1 = *(const bf16x8*)&Ks[buf][(jf * 16 + c) * LP + 32 + q * 8];
      s[jf] = __builtin_amdgcn_mfma_f32_16x16x32_bf16(aq1, bk1, s[jf], 0, 0, 0);
    }

    const bool need_mask = (j0 <= wi1);
    const bool full = ((float)(j0 + 63 - wi0) <= zz);

    if (full){
      if (need_mask){
#pragma unroll
        for (int jf = 0; jf < 4; ++jf){
          const int j = j0 + jf * 16 + c;
#pragma unroll
          for (int r = 0; r < 4; ++r){
            float p = fast_exp2(s[jf][r] * kexp);
            p = (j >= i_row[r]) ? p : 0.f;
            d1[r] += p;
            Ps[w][(q * 4 + r) * LP + jf * 16 + c] = f2bf_fast(p);
          }
        }
      } else {
#pragma unroll
        for (int jf = 0; jf < 4; ++jf){
#pragma unroll
          for (int r = 0; r < 4; ++r){
            float p = fast_exp2(s[jf][r] * kexp);
            d1[r] += p;
            Ps[w][(q * 4 + r) * LP + jf * 16 + c] = f2bf_fast(p);
          }
        }
      }
    } else {
      float fjR[4];
#pragma unroll
      for (int jf = 0; jf < 4; ++jf) fjR[jf] = (float)(j0 + jf * 16 + c) * (1.0f / R_SPAN);
      if (need_mask){
#pragma unroll
        for (int jf = 0; jf < 4; ++jf){
          const int j = j0 + jf * 16 + c;
#pragma unroll
          for (int r = 0; r < 4; ++r){
            float p = fast_exp2(s[jf][r] * kexp);
            p = (j >= i_row[r]) ? p : 0.f;
            float chi = fminf(fmaxf(ar4[r] - fjR[jf], 0.f), 1.f);
            float pc = p * chi;
            d1[r] += pc;
            Ps[w][(q * 4 + r) * LP + jf * 16 + c] = f2bf_fast(pc);
          }
        }
      } else {
#pragma unroll
        for (int jf = 0; jf < 4; ++jf){
#pragma unroll
          for (int r = 0; r < 4; ++r){
            float p = fast_exp2(s[jf][r] * kexp);
            float chi = fminf(fmaxf(ar4[r] - fjR[jf], 0.f), 1.f);
            float pc = p * chi;
            d1[r] += pc;
            Ps[w][(q * 4 + r) * LP + jf * 16 + c] = f2bf_fast(pc);
          }
        }
      }
    }

    // O += P V  (Ps per-wave: no block barrier needed)
    {
      bf16x8 pa0 = *(const bf16x8*)&Ps[w][c * LP + q * 8];
      bf16x8 pa1 = *(const bf16x8*)&Ps[w][c * LP + 32 + q * 8];
#pragma unroll
      for (int nf = 0; nf < 4; ++nf){
        bf16x8 bv0 = *(const bf16x8*)&Vt[buf][(nf * 16 + c) * LP + q * 8];
        o[nf] = __builtin_amdgcn_mfma_f32_16x16x32_bf16(pa0, bv0, o[nf], 0, 0, 0);
        bf16x8 bv1 = *(const bf16x8*)&Vt[buf][(nf * 16 + c) * LP + 32 + q * 8];
        o[nf] = __builtin_amdgcn_mfma_f32_16x16x32_bf16(pa1, bv1, o[nf], 0, 0, 0);
      }
    }
  }

  // epilogue: reduce d1 across 16 c-lanes, renormalize, write bf16
#pragma unroll
  for (int r = 0; r < 4; ++r){
    float a1 = d1[r];
    a1 += __shfl_xor(a1, 1, 64);
    a1 += __shfl_xor(a1, 2, 64);
    a1 += __shfl_xor(a1, 4, 64);
    a1 += __shfl_xor(a1, 8, 64);
    const float inv = 1.0f / (a1 + 1e-20f);
    const size_t rowbase = base + (size_t)i_row[r] * D_MODEL;
#pragma unroll
    for (int nf = 0; nf < 4; ++nf){
      Og[rowbase + nf * 16 + c] = f2bf_fast(o[nf][r] * inv);
    }
  }
}

// ---------------- launcher ----------------
extern "C" void kernel_launch(void* const* d_in, const int* in_sizes, int n_in,
                              void* d_out, int out_size, void* d_ws, size_t ws_size,
                              hipStream_t stream)
{
  const float* x     = (const float*)d_in[0];
  const float* Wq    = (const float*)d_in[1];
  const float* Wk    = (const float*)d_in[2];
  const float* Wv    = (const float*)d_in[3];
  const float* Wo    = (const float*)d_in[4];
  const float* bo    = (const float*)d_in[5];
  const float* Wspan = (const float*)d_in[6];
  const float* bspan = (const float*)d_in[7];

  const size_t MT = (size_t)4 * T_SEQ;  // 4096 rows

  ushort_t* x_bf = (ushort_t*)d_ws;                       // 4096*1024 bf16
  ushort_t* w_bf = x_bf + MT * D_MODEL;                   // 4 * 1024*1024 bf16
  ushort_t* qkv  = w_bf + (size_t)4 * D_MODEL * D_MODEL;  // Q,K row-major; V transposed
  ushort_t* attn = qkv + (size_t)3 * MT * D_MODEL;        // 4096*1024 bf16
  float* xmean   = (float*)(attn + MT * D_MODEL);         // 4*1024 f32
  float* zsp     = xmean + 4 * D_MODEL;                   // 64 f32

  conv_all<<<dim3(1024, 8), 256, 0, stream>>>(x, Wq, Wk, Wv, Wo, x_bf, w_bf);
  mean_kernel<<<dim3(16, 4), 256, 0, stream>>>(x, xmean);
  span_kernel<<<dim3(16, 4), 64, 0, stream>>>(xmean, Wspan, bspan, zsp);

  // fused Q,K,V projections (V written transposed)
  gemm_bt<0><<<dim3(8, 32, 3), 512, 0, stream>>>(x_bf, w_bf, qkv, nullptr, 4096, 1024, 1024);

  attn_kernel<<<dim3(512), 512, 0, stream>>>(qkv, qkv + MT * D_MODEL,
                                             qkv + 2 * MT * D_MODEL, zsp, attn);

  // output projection + bias, fp32 out
  gemm_bt<1><<<dim3(8, 32, 1), 512, 0, stream>>>(attn, w_bf + (size_t)3 * D_MODEL * D_MODEL,
                                                 d_out, bo, 4096, 1024, 1024);
}

// Round 9
// 188.619 us; speedup vs baseline: 1.0910x; 1.0150x over previous
//
#include <hip/hip_runtime.h>

#define T_SEQ 1024
#define D_MODEL 1024
#define NH 16
#define DH 64
#define R_SPAN 256.0f

typedef unsigned short ushort_t;
typedef __attribute__((ext_vector_type(8))) short bf16x8;
typedef __attribute__((ext_vector_type(4))) float f32x4;

// RNE conversion (input conversion — feeds all GEMMs)
__device__ __forceinline__ ushort_t f2bf(float f){
  union { float f; unsigned u; } v; v.f = f;
  unsigned r = v.u + 0x7fffu + ((v.u >> 16) & 1u);
  return (ushort_t)(r >> 16);
}

// round-half-up: 2 VALU ops, same 2^-9 rel-err bound (ties only differ)
__device__ __forceinline__ ushort_t f2bf_fast(float f){
  union { float f; unsigned u; } v; v.f = f;
  return (ushort_t)((v.u + 0x8000u) >> 16);
}

__device__ __forceinline__ float fast_exp2(float x){
#if __has_builtin(__builtin_amdgcn_exp2f)
  return __builtin_amdgcn_exp2f(x);
#else
  return __expf(x * 0.69314718056f);
#endif
}

// barrier that drains LDS (lgkmcnt=0) but leaves global loads in flight
__device__ __forceinline__ void barrier_lds_only(){
  __builtin_amdgcn_s_waitcnt(0xC07F);
  __builtin_amdgcn_s_barrier();
}

typedef __attribute__((address_space(1))) void GV;
typedef __attribute__((address_space(3))) void LV;
__device__ __forceinline__ void gld16(const void* g, void* l){
  __builtin_amdgcn_global_load_lds((GV*)g, (LV*)l, 16, 0, 0);
}

// ---------------- merged conversion kernel ----------------
__global__ void conv_all(const float* __restrict__ x,
                         const float* s1, const float* s2, const float* s3, const float* s4,
                         ushort_t* __restrict__ x_bf, ushort_t* __restrict__ w_bf){
  const int chunk = blockIdx.y;
  const float* src;
  ushort_t* dst;
  if (chunk < 4){
    src = x + ((size_t)chunk << 20);
    dst = x_bf + ((size_t)chunk << 20);
  } else {
    const float* ws[4] = {s1, s2, s3, s4};
    src = ws[chunk - 4];
    dst = w_bf + ((size_t)(chunk - 4) << 20);
  }
  const int i = (blockIdx.x * 256 + threadIdx.x) * 4;
  float4 v = *(const float4*)(src + i);
  ushort4 o; o.x = f2bf(v.x); o.y = f2bf(v.y); o.z = f2bf(v.z); o.w = f2bf(v.w);
  *(ushort4*)(dst + i) = o;
}

// ---------------- mean over T ----------------
__global__ void mean_kernel(const float* __restrict__ x, float* __restrict__ xmean){
  const int b = blockIdx.y, d0 = blockIdx.x * 64;
  const int dl = threadIdx.x & 63, tg = threadIdx.x >> 6;
  const float* p = x + (size_t)b * T_SEQ * D_MODEL + d0 + dl;
  float s = 0.f;
  for (int t = tg * 256; t < tg * 256 + 256; ++t) s += p[(size_t)t * D_MODEL];
  __shared__ float red[4][64];
  red[tg][dl] = s;
  __syncthreads();
  if (tg == 0){
    float tot = red[0][dl] + red[1][dl] + red[2][dl] + red[3][dl];
    xmean[b * D_MODEL + d0 + dl] = tot * (1.0f / T_SEQ);
  }
}

// ---------------- span net ----------------
__global__ void span_kernel(const float* __restrict__ xmean, const float* __restrict__ Wspan,
                            const float* __restrict__ bspan, float* __restrict__ z){
  const int h = blockIdx.x, b = blockIdx.y, l = threadIdx.x;
  const float* xm = xmean + b * D_MODEL;
  const float* wv = Wspan + h * D_MODEL;
  float s = 0.f;
  for (int i = l; i < D_MODEL; i += 64) s += xm[i] * wv[i];
  for (int off = 32; off; off >>= 1) s += __shfl_down(s, off, 64);
  if (l == 0){
    float logit = s + bspan[h];
    z[b * NH + h] = (float)T_SEQ / (1.0f + __expf(-logit));
  }
}

// ---------------- GEMM: C = A * B^T, 128x128 tile, 8 waves (512 thr) ----------
template<int FP32OUT>
__global__ __launch_bounds__(512) void gemm_bt(
    const ushort_t* __restrict__ A,
    const ushort_t* __restrict__ B,
    void* __restrict__ C,
    const float* __restrict__ bias,
    const int M, const int N, const int K)
{
  __shared__ ushort_t At[2][128 * 32];
  __shared__ ushort_t Bt[2][128 * 32];

  const int z = blockIdx.z;
  const ushort_t* Bz = B + (size_t)z * N * K;

  const int tid = threadIdx.x;
  const int w = tid >> 6, lane = tid & 63;
  const int q = lane >> 4, c = lane & 15;
  const int m0 = blockIdx.y * 128, n0 = blockIdx.x * 128;
  const int wm = (w >> 2) * 64, wn = (w & 3) * 32;

  const int lr = lane >> 2;
  const int lc = (lane & 3) * 8;

  f32x4 acc[4][2] = {};

  const ushort_t* ga0 = A  + (size_t)(m0 + w * 16 + lr) * K + lc;
  const ushort_t* gb0 = Bz + (size_t)(n0 + w * 16 + lr) * K + lc;

  const int S = K >> 5;
  gld16(ga0, &At[0][(w * 16) * 32]);
  gld16(gb0, &Bt[0][(w * 16) * 32]);

  for (int s = 0; s < S; ++s){
    __syncthreads();  // drains stage(s) [issued a full compute phase ago]
    if (s + 1 < S){
      const int k0 = (s + 1) << 5;
      const int nb = (s + 1) & 1;
      gld16(ga0 + k0, &At[nb][(w * 16) * 32]);
      gld16(gb0 + k0, &Bt[nb][(w * 16) * 32]);
    }
    const ushort_t* at = At[s & 1];
    const ushort_t* bt = Bt[s & 1];

    bf16x8 af[4], bfv[2];
#pragma unroll
    for (int i = 0; i < 4; ++i) af[i]  = *(const bf16x8*)&at[(wm + i * 16 + c) * 32 + q * 8];
#pragma unroll
    for (int j = 0; j < 2; ++j) bfv[j] = *(const bf16x8*)&bt[(wn + j * 16 + c) * 32 + q * 8];
#pragma unroll
    for (int i = 0; i < 4; ++i)
#pragma unroll
      for (int j = 0; j < 2; ++j)
        acc[i][j] = __builtin_amdgcn_mfma_f32_16x16x32_bf16(af[i], bfv[j], acc[i][j], 0, 0, 0);
  }

  if (FP32OUT){
#pragma unroll
    for (int i = 0; i < 4; ++i){
#pragma unroll
      for (int j = 0; j < 2; ++j){
        const int row = m0 + wm + i * 16 + q * 4;
        const int col = n0 + wn + j * 16 + c;
#pragma unroll
        for (int r = 0; r < 4; ++r)
          ((float*)C)[(size_t)(row + r) * N + col] = acc[i][j][r] + bias[col];
      }
    }
  } else if (z == 2){
    // V: write transposed vt[b][n][t] so attn can stage V^T directly
    ushort_t* Cv = (ushort_t*)C + (size_t)2 * M * N;
    const int bb = m0 >> 10;
#pragma unroll
    for (int i = 0; i < 4; ++i){
#pragma unroll
      for (int j = 0; j < 2; ++j){
        const int col = n0 + wn + j * 16 + c;
        const int t0 = (m0 & 1023) + wm + i * 16 + q * 4;
        ushort4 pk;
        pk.x = f2bf_fast(acc[i][j][0]); pk.y = f2bf_fast(acc[i][j][1]);
        pk.z = f2bf_fast(acc[i][j][2]); pk.w = f2bf_fast(acc[i][j][3]);
        *(ushort4*)&Cv[((size_t)bb << 20) + (size_t)col * 1024 + t0] = pk;
      }
    }
  } else {
#pragma unroll
    for (int i = 0; i < 4; ++i){
#pragma unroll
      for (int j = 0; j < 2; ++j){
        const int row = m0 + wm + i * 16 + q * 4;
        const int col = n0 + wn + j * 16 + c;
#pragma unroll
        for (int r = 0; r < 4; ++r)
          ((ushort_t*)C + (size_t)z * M * N)[(size_t)(row + r) * N + col] = f2bf_fast(acc[i][j][r]);
      }
    }
  }
}

// ---------------- flash attention with adaptive span (v9) ----------------
// v8 + denominator via MFMA row-sum: acc_d = P x ones reuses the pa0/pa1
// fragments, replacing 16 v_add/tile and the whole epilogue shuffle tree
// (every c-lane holds the full row sum). chi lane-constant hoisted.
#define LP 72
__global__ __launch_bounds__(512) void attn_kernel(
    const ushort_t* __restrict__ Qg,
    const ushort_t* __restrict__ Kg,
    const ushort_t* __restrict__ Vtg,
    const float* __restrict__ zspan,
    ushort_t* __restrict__ Og)
{
  __shared__ ushort_t Qs[128 * LP];
  __shared__ ushort_t Ks[2][64 * LP];
  __shared__ ushort_t Vt[2][64 * LP];  // [d][j]
  __shared__ ushort_t Ps[8][16 * LP];  // per-wave P band

  // id = (g/8)*64 + qt*8 + (g%8), g = b*16+h  ->  id%8 == g%8 (XCD locality)
  const int id = blockIdx.x;
  const int qt = (id >> 3) & 7;
  const int g  = ((id >> 6) << 3) | (id & 7);
  const int b = g >> 4, h = g & 15;
  const int q0 = qt * 128;
  const int tid = threadIdx.x, w = tid >> 6, lane = tid & 63;
  const int q = lane >> 4, c = lane & 15;

  const size_t base = ((size_t)b * T_SEQ) * D_MODEL + (size_t)h * DH;
  const ushort_t* vtb = Vtg + ((size_t)b << 20) + ((size_t)h << 16);

  // load Q tile (128x64): 512 threads x 32 B
  {
    const int row = tid >> 2, seg = tid & 3;
    const uint4* gq = (const uint4*)(Qg + base + (size_t)(q0 + row) * D_MODEL);
    uint4* qs = (uint4*)&Qs[row * LP];
    qs[seg * 2]     = gq[seg * 2];
    qs[seg * 2 + 1] = gq[seg * 2 + 1];
  }

  const float zz = zspan[b * NH + h];
  const int jend = min(T_SEQ, (int)(q0 + 127 + R_SPAN + zz) + 1);

  f32x4 acc_d = {};  // denominator row-sums via MFMA (P x ones)
  f32x4 o[4] = {};

  // all-ones bf16 B-fragment (1.0 = 0x3F80)
  bf16x8 ones8;
#pragma unroll
  for (int i = 0; i < 8; ++i) ones8[i] = (short)0x3F80;

  const int wi0 = q0 + w * 16, wi1 = wi0 + 15;
  int i_row[4];
  float ar4[4];
#pragma unroll
  for (int r = 0; r < 4; ++r){
    i_row[r] = wi0 + q * 4 + r;
    ar4[r] = (R_SPAN + zz + (float)i_row[r]) * (1.0f / R_SPAN);
  }
  // chi lane-constant: (jf*16 + c)/R, hoisted out of the j-loop
  float cjR[4];
#pragma unroll
  for (int jf = 0; jf < 4; ++jf) cjR[jf] = (float)(jf * 16 + c) * (1.0f / R_SPAN);
  const float kexp = 0.125f * 1.44269504f;

  // staging coords: 64 rows x 8 segs of 8 elements
  const int srow = tid >> 3, sseg = tid & 7;
  const ushort_t* kg = Kg + base + sseg * 8;
  const ushort_t* vg = vtb + (size_t)srow * 1024 + sseg * 8;

  // prefetch first tile
  uint4 kreg = *(const uint4*)(kg + (size_t)(q0 + srow) * D_MODEL);
  uint4 vreg = *(const uint4*)(vg + q0);

  // Qs visible to all waves; hoist Q A-fragments (constant over j-loop)
  __syncthreads();
  const bf16x8 aq0 = *(const bf16x8*)&Qs[(w * 16 + c) * LP + q * 8];
  const bf16x8 aq1 = *(const bf16x8*)&Qs[(w * 16 + c) * LP + 32 + q * 8];

  int it = 0;
  for (int j0 = q0; j0 < jend; j0 += 64, ++it){
    const int buf = it & 1;
    // write tile j0 (regs were loaded >=1 compute-phase ago)
    *(uint4*)&Ks[buf][srow * LP + sseg * 8] = kreg;
    *(uint4*)&Vt[buf][srow * LP + sseg * 8] = vreg;
    if (j0 + 64 < jend){
      kreg = *(const uint4*)(kg + (size_t)(j0 + 64 + srow) * D_MODEL);
      vreg = *(const uint4*)(vg + j0 + 64);
    }
    barrier_lds_only();  // LDS writes visible; prefetch stays in flight

    // per-wave skip: fully causal-masked or fully outside span
    if (j0 + 63 < wi0) continue;
    if ((float)(j0 - wi1) > R_SPAN + zz) continue;

    // S = Q K^T  (16x64 band per wave)
    f32x4 s[4] = {};
#pragma unroll
    for (int jf = 0; jf < 4; ++jf){
      bf16x8 bk0 = *(const bf16x8*)&Ks[buf][(jf * 16 + c) * LP + q * 8];
      s[jf] = __builtin_amdgcn_mfma_f32_16x16x32_bf16(aq0, bk0, s[jf], 0, 0, 0);
      bf16x8 bk1 = *(const bf16x8*)&Ks[buf][(jf * 16 + c) * LP + 32 + q * 8];
      s[jf] = __builtin_amdgcn_mfma_f32_16x16x32_bf16(aq1, bk1, s[jf], 0, 0, 0);
    }

    const bool need_mask = (j0 <= wi1);
    const bool full = ((float)(j0 + 63 - wi0) <= zz);

    if (full){
      if (need_mask){
#pragma unroll
        for (int jf = 0; jf < 4; ++jf){
          const int j = j0 + jf * 16 + c;
#pragma unroll
          for (int r = 0; r < 4; ++r){
            float p = fast_exp2(s[jf][r] * kexp);
            p = (j >= i_row[r]) ? p : 0.f;
            Ps[w][(q * 4 + r) * LP + jf * 16 + c] = f2bf_fast(p);
          }
        }
      } else {
#pragma unroll
        for (int jf = 0; jf < 4; ++jf){
#pragma unroll
          for (int r = 0; r < 4; ++r){
            float p = fast_exp2(s[jf][r] * kexp);
            Ps[w][(q * 4 + r) * LP + jf * 16 + c] = f2bf_fast(p);
          }
        }
      }
    } else {
      // ramp: chi = clamp((ar4[r] - j0/R) - cjR[jf], 0, 1)
      const float arj = (float)j0 * (1.0f / R_SPAN);
      if (need_mask){
#pragma unroll
        for (int jf = 0; jf < 4; ++jf){
          const int j = j0 + jf * 16 + c;
#pragma unroll
          for (int r = 0; r < 4; ++r){
            float p = fast_exp2(s[jf][r] * kexp);
            p = (j >= i_row[r]) ? p : 0.f;
            float chi = fminf(fmaxf((ar4[r] - arj) - cjR[jf], 0.f), 1.f);
            Ps[w][(q * 4 + r) * LP + jf * 16 + c] = f2bf_fast(p * chi);
          }
        }
      } else {
#pragma unroll
        for (int jf = 0; jf < 4; ++jf){
#pragma unroll
          for (int r = 0; r < 4; ++r){
            float p = fast_exp2(s[jf][r] * kexp);
            float chi = fminf(fmaxf((ar4[r] - arj) - cjR[jf], 0.f), 1.f);
            Ps[w][(q * 4 + r) * LP + jf * 16 + c] = f2bf_fast(p * chi);
          }
        }
      }
    }

    // O += P V ; acc_d += P x ones (reuses pa fragments; rowsum in all lanes)
    {
      bf16x8 pa0 = *(const bf16x8*)&Ps[w][c * LP + q * 8];
      bf16x8 pa1 = *(const bf16x8*)&Ps[w][c * LP + 32 + q * 8];
      acc_d = __builtin_amdgcn_mfma_f32_16x16x32_bf16(pa0, ones8, acc_d, 0, 0, 0);
      acc_d = __builtin_amdgcn_mfma_f32_16x16x32_bf16(pa1, ones8, acc_d, 0, 0, 0);
#pragma unroll
      for (int nf = 0; nf < 4; ++nf){
        bf16x8 bv0 = *(const bf16x8*)&Vt[buf][(nf * 16 + c) * LP + q * 8];
        o[nf] = __builtin_amdgcn_mfma_f32_16x16x32_bf16(pa0, bv0, o[nf], 0, 0, 0);
        bf16x8 bv1 = *(const bf16x8*)&Vt[buf][(nf * 16 + c) * LP + 32 + q * 8];
        o[nf] = __builtin_amdgcn_mfma_f32_16x16x32_bf16(pa1, bv1, o[nf], 0, 0, 0);
      }
    }
  }

  // epilogue: acc_d[r] already holds the full row-sum in every c-lane
#pragma unroll
  for (int r = 0; r < 4; ++r){
    const float inv = 1.0f / (acc_d[r] + 1e-20f);
    const size_t rowbase = base + (size_t)i_row[r] * D_MODEL;
#pragma unroll
    for (int nf = 0; nf < 4; ++nf){
      Og[rowbase + nf * 16 + c] = f2bf_fast(o[nf][r] * inv);
    }
  }
}

// ---------------- launcher ----------------
extern "C" void kernel_launch(void* const* d_in, const int* in_sizes, int n_in,
                              void* d_out, int out_size, void* d_ws, size_t ws_size,
                              hipStream_t stream)
{
  const float* x     = (const float*)d_in[0];
  const float* Wq    = (const float*)d_in[1];
  const float* Wk    = (const float*)d_in[2];
  const float* Wv    = (const float*)d_in[3];
  const float* Wo    = (const float*)d_in[4];
  const float* bo    = (const float*)d_in[5];
  const float* Wspan = (const float*)d_in[6];
  const float* bspan = (const float*)d_in[7];

  const size_t MT = (size_t)4 * T_SEQ;  // 4096 rows

  ushort_t* x_bf = (ushort_t*)d_ws;                       // 4096*1024 bf16
  ushort_t* w_bf = x_bf + MT * D_MODEL;                   // 4 * 1024*1024 bf16
  ushort_t* qkv  = w_bf + (size_t)4 * D_MODEL * D_MODEL;  // Q,K row-major; V transposed
  ushort_t* attn = qkv + (size_t)3 * MT * D_MODEL;        // 4096*1024 bf16
  float* xmean   = (float*)(attn + MT * D_MODEL);         // 4*1024 f32
  float* zsp     = xmean + 4 * D_MODEL;                   // 64 f32

  conv_all<<<dim3(1024, 8), 256, 0, stream>>>(x, Wq, Wk, Wv, Wo, x_bf, w_bf);
  mean_kernel<<<dim3(16, 4), 256, 0, stream>>>(x, xmean);
  span_kernel<<<dim3(16, 4), 64, 0, stream>>>(xmean, Wspan, bspan, zsp);

  // fused Q,K,V projections (V written transposed)
  gemm_bt<0><<<dim3(8, 32, 3), 512, 0, stream>>>(x_bf, w_bf, qkv, nullptr, 4096, 1024, 1024);

  attn_kernel<<<dim3(512), 512, 0, stream>>>(qkv, qkv + MT * D_MODEL,
                                             qkv + 2 * MT * D_MODEL, zsp, attn);

  // output projection + bias, fp32 out
  gemm_bt<1><<<dim3(8, 32, 1), 512, 0, stream>>>(attn, w_bf + (size_t)3 * D_MODEL * D_MODEL,
                                                 d_out, bo, 4096, 1024, 1024);
}